// Round 1
// baseline (186.822 us; speedup 1.0000x reference)
//
#include <hip/hip_runtime.h>
#include <math.h>

// Problem constants (B, C, H, W) = (16, 256, 64, 64), GROUPS=4, RATIO=2
#define B_   16
#define C_   256
#define H_   64
#define W_   64
#define G_   4
#define HO_  128
#define WO_  128

// ---------------------------------------------------------------------------
// Kernel 1: per (b,h,w) pixel -> 32 off-channels + 32 scope-channels,
// sigmoid gate, pixel-shuffle analytically, emit (ix,iy) float2 per
// (b, g, ho, wo). Coord buffer: 16*4*128*128 float2 = 8 MiB in d_ws.
// ---------------------------------------------------------------------------
__global__ __launch_bounds__(256) void offsets_kernel(
    const float* __restrict__ x,        // (B, 256, 64, 64)
    const float* __restrict__ w_off,    // (32, 256)
    const float* __restrict__ b_off,    // (32,)
    const float* __restrict__ w_scope,  // (4, 8, 64)
    const float* __restrict__ b_scope,  // (32,)
    float2* __restrict__ coords)        // (B, 4, 128, 128)
{
    __shared__ float wof[256][32];   // [i][o]   transposed w_off, 32 KB
    __shared__ float wsc[64][32];    // [i2][gi*8+oi] transposed w_scope, 8 KB

    const int tid = threadIdx.x;
    // conflict-free LDS writes (contiguous across lanes)
    for (int k = tid; k < 256 * 32; k += 256) {
        int i = k >> 5, o = k & 31;
        wof[i][o] = w_off[o * 256 + i];
    }
    for (int k = tid; k < 64 * 32; k += 256) {
        int i2 = k >> 5, q = k & 31;
        int gi = q >> 3, oi = q & 7;
        wsc[i2][q] = w_scope[gi * 512 + oi * 64 + i2];
    }
    __syncthreads();

    const int idx = blockIdx.x * 256 + tid;
    const int w = idx & 63;
    const int h = (idx >> 6) & 63;
    const int b = idx >> 12;

    const float* xp = x + (size_t)b * C_ * (H_ * W_) + h * W_ + w;

    float aoff[32];
    float asc[32];
#pragma unroll
    for (int o = 0; o < 32; ++o) { aoff[o] = 0.f; asc[o] = 0.f; }

#pragma unroll
    for (int gi = 0; gi < 4; ++gi) {          // gi compile-time -> static asc idx
#pragma unroll 4
        for (int i2 = 0; i2 < 64; ++i2) {
            const int i = gi * 64 + i2;
            const float xv = xp[(size_t)i * (H_ * W_)];
            const float4* wp = (const float4*)(&wof[i][0]);
#pragma unroll
            for (int o4 = 0; o4 < 8; ++o4) {
                float4 wv = wp[o4];
                aoff[o4 * 4 + 0] += xv * wv.x;
                aoff[o4 * 4 + 1] += xv * wv.y;
                aoff[o4 * 4 + 2] += xv * wv.z;
                aoff[o4 * 4 + 3] += xv * wv.w;
            }
            const float4* sp = (const float4*)(&wsc[i2][gi * 8]);
            float4 s0 = sp[0], s1 = sp[1];
            asc[gi * 8 + 0] += xv * s0.x;
            asc[gi * 8 + 1] += xv * s0.y;
            asc[gi * 8 + 2] += xv * s0.z;
            asc[gi * 8 + 3] += xv * s0.w;
            asc[gi * 8 + 4] += xv * s1.x;
            asc[gi * 8 + 5] += xv * s1.y;
            asc[gi * 8 + 6] += xv * s1.z;
            asc[gi * 8 + 7] += xv * s1.w;
        }
    }

    float f[32];
#pragma unroll
    for (int o = 0; o < 32; ++o) {
        float offv = aoff[o] + b_off[o];
        float scv  = asc[o] + b_scope[o];
        float sg   = 1.f / (1.f + expf(-scv));
        f[o] = sg * 0.5f * offv;
    }

    // pixel shuffle: ps[b, co, 2h+r1, 2w+r2] = f[co*4 + r1*2 + r2]
    // group gi: og0 = ps channel 2*gi, og1 = ps channel 2*gi+1
    // ix = (wo - 0.5 + og0)*0.5 ; iy = (ho - 0.5 + og1)*0.5 ; clip [0, 63]
#pragma unroll
    for (int gi = 0; gi < 4; ++gi) {
#pragma unroll
        for (int r1 = 0; r1 < 2; ++r1) {
#pragma unroll
            for (int r2 = 0; r2 < 2; ++r2) {
                const int ho = 2 * h + r1;
                const int wo = 2 * w + r2;
                const float og0 = f[8 * gi + 2 * r1 + r2];
                const float og1 = f[8 * gi + 4 + 2 * r1 + r2];
                float ix = ((float)wo - 0.5f + og0) * 0.5f;
                float iy = ((float)ho - 0.5f + og1) * 0.5f;
                ix = fminf(fmaxf(ix, 0.f), (float)(W_ - 1));
                iy = fminf(fmaxf(iy, 0.f), (float)(H_ - 1));
                coords[(((size_t)b * G_ + gi) * HO_ + ho) * WO_ + wo] =
                    make_float2(ix, iy);
            }
        }
    }
}

// ---------------------------------------------------------------------------
// Kernel 2: bilinear sampling. One thread per (b, g, ho, wo); loops over the
// group's 64 channels (channel c = cc*4 + g). Writes coalesced along wo.
// Block = 256 threads = 2 ho-rows x 128 wo. Grid = (64, 4, 16).
// ---------------------------------------------------------------------------
__global__ __launch_bounds__(256) void sample_kernel(
    const float* __restrict__ x,        // (B, 256, 64, 64)
    const float2* __restrict__ coords,  // (B, 4, 128, 128)
    float* __restrict__ out)            // (B, 256, 128, 128)
{
    const int wo = threadIdx.x & 127;
    const int ho = (blockIdx.x << 1) + (threadIdx.x >> 7);
    const int g  = blockIdx.y;
    const int b  = blockIdx.z;

    const float2 c =
        coords[(((size_t)b * G_ + g) * HO_ + ho) * WO_ + wo];
    const float ix = c.x, iy = c.y;

    const float x0f = floorf(ix);
    const float y0f = floorf(iy);
    const float wx = ix - x0f;
    const float wy = iy - y0f;
    int x0 = (int)x0f;
    int y0 = (int)y0f;
    x0 = max(0, min(x0, W_ - 1));
    y0 = max(0, min(y0, H_ - 1));
    const int x1 = min(x0 + 1, W_ - 1);
    const int y1 = min(y0 + 1, H_ - 1);

    const float w00 = (1.f - wy) * (1.f - wx);
    const float w01 = (1.f - wy) * wx;
    const float w10 = wy * (1.f - wx);
    const float w11 = wy * wx;

    const int p00 = y0 * W_ + x0;
    const int p01 = y0 * W_ + x1;
    const int p10 = y1 * W_ + x0;
    const int p11 = y1 * W_ + x1;

    const float* xb = x + (size_t)b * C_ * (H_ * W_) + (size_t)g * (H_ * W_);
    float* ob = out + (size_t)b * C_ * (HO_ * WO_) + (size_t)g * (HO_ * WO_) +
                ho * WO_ + wo;

#pragma unroll 4
    for (int cc = 0; cc < 64; ++cc) {
        const float* pl = xb + (size_t)cc * 4 * (H_ * W_);
        const float v = pl[p00] * w00 + pl[p01] * w01 +
                        pl[p10] * w10 + pl[p11] * w11;
        ob[(size_t)cc * 4 * (HO_ * WO_)] = v;
    }
}

// ---------------------------------------------------------------------------
extern "C" void kernel_launch(void* const* d_in, const int* in_sizes, int n_in,
                              void* d_out, int out_size, void* d_ws, size_t ws_size,
                              hipStream_t stream) {
    const float* x       = (const float*)d_in[0];
    const float* w_off   = (const float*)d_in[1];
    const float* b_off   = (const float*)d_in[2];
    const float* w_scope = (const float*)d_in[3];
    const float* b_scope = (const float*)d_in[4];
    float* out = (float*)d_out;
    float2* coords = (float2*)d_ws;   // needs 16*4*128*128*8 = 8 MiB

    offsets_kernel<<<dim3((B_ * H_ * W_) / 256), 256, 0, stream>>>(
        x, w_off, b_off, w_scope, b_scope, coords);
    sample_kernel<<<dim3(HO_ / 2, G_, B_), 256, 0, stream>>>(x, coords, out);
}

// Round 2
// 131.671 us; speedup vs baseline: 1.4189x; 1.4189x over previous
//
#include <hip/hip_runtime.h>
#include <math.h>

// Problem constants (B, C, H, W) = (16, 256, 64, 64), GROUPS=4, RATIO=2
#define B_   16
#define C_   256
#define H_   64
#define W_   64
#define G_   4
#define HO_  128
#define WO_  128
#define HW_  (H_ * W_)

// ---------------------------------------------------------------------------
// Kernel 1: split-K offsets. 4 threads per pixel (t = tid&3), each owns
// channels [64t, 64t+64). aoff reduced via lane-butterfly; asc for group t
// fully owned by thread t. Emits (ix,iy) float2 per (b, g, ho, wo) in d_ws.
// ---------------------------------------------------------------------------
__global__ __launch_bounds__(256) void offsets_kernel(
    const float* __restrict__ x,        // (B, 256, 64, 64)
    const float* __restrict__ w_off,    // (32, 256)
    const float* __restrict__ b_off,    // (32,)
    const float* __restrict__ w_scope,  // (4, 8, 64)
    const float* __restrict__ b_scope,  // (32,)
    float2* __restrict__ coords)        // (B, 4, 128, 128)
{
    // wof: row i holds w_off[:, i], float4-chunk o4 stored at slot (o4 + i/64)&7
    // so the 4 channel-quarters read 4 distinct bank quadruples (no conflict).
    __shared__ float wof[256][32];   // 32 KB
    __shared__ float wsc[64][32];    // [i2][gi*8+oi], 8 KB

    const int tid = threadIdx.x;
    for (int k = tid; k < 256 * 32; k += 256) {
        int i = k >> 5, o = k & 31;
        int slot = ((o >> 2) + (i >> 6)) & 7;
        wof[i][slot * 4 + (o & 3)] = w_off[o * 256 + i];
    }
    for (int k = tid; k < 64 * 32; k += 256) {
        int i2 = k >> 5, q = k & 31;
        int gi = q >> 3, oi = q & 7;
        wsc[i2][q] = w_scope[gi * 512 + oi * 64 + i2];
    }
    __syncthreads();

    const int t   = tid & 3;                 // channel quarter / group
    const int pix = blockIdx.x * 64 + (tid >> 2);
    const int w = pix & 63;
    const int h = (pix >> 6) & 63;
    const int b = pix >> 12;

    const float* xq = x + (size_t)b * C_ * HW_ + (size_t)t * 64 * HW_ +
                      h * W_ + w;

    float aoff[32];
    float asc[8];
#pragma unroll
    for (int o = 0; o < 32; ++o) aoff[o] = 0.f;
#pragma unroll
    for (int o = 0; o < 8; ++o) asc[o] = 0.f;

#pragma unroll 4
    for (int i2 = 0; i2 < 64; ++i2) {
        const float xv = xq[(size_t)i2 * HW_];
        const int row = t * 64 + i2;
        const float4* wp = (const float4*)(&wof[row][0]);
#pragma unroll
        for (int o4 = 0; o4 < 8; ++o4) {
            float4 wv = wp[(o4 + t) & 7];    // undo store swizzle
            aoff[o4 * 4 + 0] += xv * wv.x;
            aoff[o4 * 4 + 1] += xv * wv.y;
            aoff[o4 * 4 + 2] += xv * wv.z;
            aoff[o4 * 4 + 3] += xv * wv.w;
        }
        const float4* sp = (const float4*)(&wsc[i2][0]) + (t * 2);
        float4 s0 = sp[0], s1 = sp[1];
        asc[0] += xv * s0.x;
        asc[1] += xv * s0.y;
        asc[2] += xv * s0.z;
        asc[3] += xv * s0.w;
        asc[4] += xv * s1.x;
        asc[5] += xv * s1.y;
        asc[6] += xv * s1.z;
        asc[7] += xv * s1.w;
    }

    // butterfly-reduce aoff across the 4 lanes of this pixel
#pragma unroll
    for (int o = 0; o < 32; ++o) {
        aoff[o] += __shfl_xor(aoff[o], 1);
        aoff[o] += __shfl_xor(aoff[o], 2);
    }

    // epilogue: this thread handles group gi == t (unrolled so all register
    // indices are compile-time constants)
#pragma unroll
    for (int gi = 0; gi < 4; ++gi) {
        if (gi == t) {
            float f[8];
#pragma unroll
            for (int j = 0; j < 8; ++j) {
                float offv = aoff[8 * gi + j] + b_off[8 * gi + j];
                float scv  = asc[j] + b_scope[8 * gi + j];
                float sg   = 1.f / (1.f + expf(-scv));
                f[j] = sg * 0.5f * offv;
            }
            // pixel shuffle: og0 = f[2*r1+r2], og1 = f[4+2*r1+r2]
#pragma unroll
            for (int r1 = 0; r1 < 2; ++r1) {
#pragma unroll
                for (int r2 = 0; r2 < 2; ++r2) {
                    const int ho = 2 * h + r1;
                    const int wo = 2 * w + r2;
                    float ix = ((float)wo - 0.5f + f[2 * r1 + r2]) * 0.5f;
                    float iy = ((float)ho - 0.5f + f[4 + 2 * r1 + r2]) * 0.5f;
                    ix = fminf(fmaxf(ix, 0.f), (float)(W_ - 1));
                    iy = fminf(fmaxf(iy, 0.f), (float)(H_ - 1));
                    coords[(((size_t)b * G_ + gi) * HO_ + ho) * WO_ + wo] =
                        make_float2(ix, iy);
                }
            }
        }
    }
}

// ---------------------------------------------------------------------------
// Kernel 2: bilinear sampling. One thread per (b, g, ho, wo); loops over the
// group's 64 channels (channel c = cc*4 + g). Writes coalesced along wo.
// ---------------------------------------------------------------------------
__global__ __launch_bounds__(256) void sample_kernel(
    const float* __restrict__ x,        // (B, 256, 64, 64)
    const float2* __restrict__ coords,  // (B, 4, 128, 128)
    float* __restrict__ out)            // (B, 256, 128, 128)
{
    const int wo = threadIdx.x & 127;
    const int ho = (blockIdx.x << 1) + (threadIdx.x >> 7);
    const int g  = blockIdx.y;
    const int b  = blockIdx.z;

    const float2 c =
        coords[(((size_t)b * G_ + g) * HO_ + ho) * WO_ + wo];
    const float ix = c.x, iy = c.y;

    const float x0f = floorf(ix);
    const float y0f = floorf(iy);
    const float wx = ix - x0f;
    const float wy = iy - y0f;
    int x0 = (int)x0f;
    int y0 = (int)y0f;
    x0 = max(0, min(x0, W_ - 1));
    y0 = max(0, min(y0, H_ - 1));
    const int x1 = min(x0 + 1, W_ - 1);
    const int y1 = min(y0 + 1, H_ - 1);

    const float w00 = (1.f - wy) * (1.f - wx);
    const float w01 = (1.f - wy) * wx;
    const float w10 = wy * (1.f - wx);
    const float w11 = wy * wx;

    const int p00 = y0 * W_ + x0;
    const int p01 = y0 * W_ + x1;
    const int p10 = y1 * W_ + x0;
    const int p11 = y1 * W_ + x1;

    const float* xb = x + (size_t)b * C_ * HW_ + (size_t)g * HW_;
    float* ob = out + (size_t)b * C_ * (HO_ * WO_) + (size_t)g * (HO_ * WO_) +
                ho * WO_ + wo;

#pragma unroll 4
    for (int cc = 0; cc < 64; ++cc) {
        const float* pl = xb + (size_t)cc * 4 * HW_;
        const float v = pl[p00] * w00 + pl[p01] * w01 +
                        pl[p10] * w10 + pl[p11] * w11;
        ob[(size_t)cc * 4 * (HO_ * WO_)] = v;
    }
}

// ---------------------------------------------------------------------------
extern "C" void kernel_launch(void* const* d_in, const int* in_sizes, int n_in,
                              void* d_out, int out_size, void* d_ws, size_t ws_size,
                              hipStream_t stream) {
    const float* x       = (const float*)d_in[0];
    const float* w_off   = (const float*)d_in[1];
    const float* b_off   = (const float*)d_in[2];
    const float* w_scope = (const float*)d_in[3];
    const float* b_scope = (const float*)d_in[4];
    float* out = (float*)d_out;
    float2* coords = (float2*)d_ws;   // 16*4*128*128 float2 = 8 MiB

    offsets_kernel<<<dim3((B_ * H_ * W_) / 64), 256, 0, stream>>>(
        x, w_off, b_off, w_scope, b_scope, coords);
    sample_kernel<<<dim3(HO_ / 2, G_, B_), 256, 0, stream>>>(x, coords, out);
}

// Round 3
// 107.859 us; speedup vs baseline: 1.7321x; 1.2208x over previous
//
#include <hip/hip_runtime.h>
#include <math.h>

// Problem constants (B, C, H, W) = (16, 256, 64, 64), GROUPS=4, RATIO=2
#define B_   16
#define C_   256
#define H_   64
#define W_   64
#define G_   4
#define HO_  128
#define WO_  128
#define HW_  (H_ * W_)
#define HOWO_ (HO_ * WO_)

// ---------------------------------------------------------------------------
// Fused kernel. One block = one input pixel row (b, h, w=0..63).
// Phase 1 (conv): 4 threads per pixel (t = tid&3), each owns channels
//   [64t, 64t+64). aoff reduced via lane butterfly; asc for group t fully
//   owned by thread t. Coords for the block's 2x128 output region go to LDS
//   (reusing the weight buffer, which is dead after the conv loop).
// Phase 2 (sample): thread = (z = tid>>7, wo = tid&127) covers ho = 2h + z,
//   loops g(4) x cc(64); writes coalesced along wo.
// ---------------------------------------------------------------------------
__global__ __launch_bounds__(256) void fused_kernel(
    const float* __restrict__ x,        // (B, 256, 64, 64)
    const float* __restrict__ w_off,    // (32, 256)
    const float* __restrict__ b_off,    // (32,)
    const float* __restrict__ w_scope,  // (4, 8, 64)
    const float* __restrict__ b_scope,  // (32,)
    float* __restrict__ out)            // (B, 256, 128, 128)
{
    __shared__ float smem[10240];                    // 40 KB
    float (*wof)[32] = (float (*)[32])smem;          // 256x32, swizzled chunks
    float (*wsc)[32] = (float (*)[32])(smem + 8192); // 64x32 [i2][gi*8+oi]
    float2* coords = (float2*)smem;                  // [g][z][wo] = 1024 f2, 8 KB

    const int tid = threadIdx.x;
    // stage weights (conflict-free, coalesced)
    for (int k = tid; k < 256 * 32; k += 256) {
        int i = k >> 5, o = k & 31;
        int slot = ((o >> 2) + (i >> 6)) & 7;        // chunk-rotation swizzle
        wof[i][slot * 4 + (o & 3)] = w_off[o * 256 + i];
    }
    for (int k = tid; k < 64 * 32; k += 256) {
        int i2 = k >> 5, q = k & 31;
        wsc[i2][q] = w_scope[(q >> 3) * 512 + (q & 7) * 64 + i2];
    }
    __syncthreads();

    const int t = tid & 3;              // channel quarter / group
    const int w = tid >> 2;             // 0..63 (pixel within row)
    const int h = blockIdx.x & 63;
    const int b = blockIdx.x >> 6;

    const float* xq = x + (size_t)b * C_ * HW_ + (size_t)t * 64 * HW_ +
                      h * W_ + w;

    float aoff[32];
    float asc[8];
#pragma unroll
    for (int o = 0; o < 32; ++o) aoff[o] = 0.f;
#pragma unroll
    for (int o = 0; o < 8; ++o) asc[o] = 0.f;

#pragma unroll 4
    for (int i2 = 0; i2 < 64; ++i2) {
        const float xv = xq[(size_t)i2 * HW_];
        const int row = t * 64 + i2;
        const float4* wp = (const float4*)(&wof[row][0]);
#pragma unroll
        for (int o4 = 0; o4 < 8; ++o4) {
            float4 wv = wp[(o4 + t) & 7];            // undo store swizzle
            aoff[o4 * 4 + 0] += xv * wv.x;
            aoff[o4 * 4 + 1] += xv * wv.y;
            aoff[o4 * 4 + 2] += xv * wv.z;
            aoff[o4 * 4 + 3] += xv * wv.w;
        }
        const float4* sp = (const float4*)(&wsc[i2][0]) + (t * 2);
        float4 s0 = sp[0], s1 = sp[1];
        asc[0] += xv * s0.x;
        asc[1] += xv * s0.y;
        asc[2] += xv * s0.z;
        asc[3] += xv * s0.w;
        asc[4] += xv * s1.x;
        asc[5] += xv * s1.y;
        asc[6] += xv * s1.z;
        asc[7] += xv * s1.w;
    }

    // butterfly-reduce aoff across the 4 lanes of this pixel
#pragma unroll
    for (int o = 0; o < 32; ++o) {
        aoff[o] += __shfl_xor(aoff[o], 1);
        aoff[o] += __shfl_xor(aoff[o], 2);
    }

    __syncthreads();   // weights dead; smem becomes the coords buffer

    // epilogue: thread (w, t) emits group-t coords for its pixel's 2x2 region
#pragma unroll
    for (int gi = 0; gi < 4; ++gi) {
        if (gi == t) {
            float f[8];
#pragma unroll
            for (int j = 0; j < 8; ++j) {
                float offv = aoff[8 * gi + j] + b_off[8 * gi + j];
                float scv  = asc[j] + b_scope[8 * gi + j];
                float sg   = 1.f / (1.f + expf(-scv));
                f[j] = sg * 0.5f * offv;
            }
#pragma unroll
            for (int r1 = 0; r1 < 2; ++r1) {
#pragma unroll
                for (int r2 = 0; r2 < 2; ++r2) {
                    const int ho = 2 * h + r1;
                    const int wo = 2 * w + r2;
                    float ix = ((float)wo - 0.5f + f[2 * r1 + r2]) * 0.5f;
                    float iy = ((float)ho - 0.5f + f[4 + 2 * r1 + r2]) * 0.5f;
                    ix = fminf(fmaxf(ix, 0.f), (float)(W_ - 1));
                    iy = fminf(fmaxf(iy, 0.f), (float)(H_ - 1));
                    coords[gi * 256 + r1 * 128 + wo] = make_float2(ix, iy);
                }
            }
        }
    }

    __syncthreads();

    // ---------------- phase 2: bilinear sampling ----------------
    const int wo = tid & 127;
    const int z  = tid >> 7;            // 0..1
    const int ho = 2 * h + z;

    const float* xb0 = x + (size_t)b * C_ * HW_;
    float* ob0 = out + (size_t)b * C_ * HOWO_ + ho * WO_ + wo;

#pragma unroll
    for (int g = 0; g < 4; ++g) {
        const float2 c = coords[g * 256 + z * 128 + wo];
        const float ix = c.x, iy = c.y;

        const float x0f = floorf(ix);
        const float y0f = floorf(iy);
        const float wx = ix - x0f;
        const float wy = iy - y0f;
        int x0 = (int)x0f;
        int y0 = (int)y0f;
        x0 = max(0, min(x0, W_ - 1));
        y0 = max(0, min(y0, H_ - 1));
        const int x1 = min(x0 + 1, W_ - 1);
        const int y1 = min(y0 + 1, H_ - 1);

        const float w00 = (1.f - wy) * (1.f - wx);
        const float w01 = (1.f - wy) * wx;
        const float w10 = wy * (1.f - wx);
        const float w11 = wy * wx;

        const int p00 = y0 * W_ + x0;
        const int p01 = y0 * W_ + x1;
        const int p10 = y1 * W_ + x0;
        const int p11 = y1 * W_ + x1;

        const float* xb = xb0 + (size_t)g * HW_;
        float* ob = ob0 + (size_t)g * HOWO_;

#pragma unroll 4
        for (int cc = 0; cc < 64; ++cc) {
            const float* pl = xb + (size_t)cc * 4 * HW_;
            const float v = pl[p00] * w00 + pl[p01] * w01 +
                            pl[p10] * w10 + pl[p11] * w11;
            ob[(size_t)cc * 4 * HOWO_] = v;
        }
    }
}

// ---------------------------------------------------------------------------
extern "C" void kernel_launch(void* const* d_in, const int* in_sizes, int n_in,
                              void* d_out, int out_size, void* d_ws, size_t ws_size,
                              hipStream_t stream) {
    const float* x       = (const float*)d_in[0];
    const float* w_off   = (const float*)d_in[1];
    const float* b_off   = (const float*)d_in[2];
    const float* w_scope = (const float*)d_in[3];
    const float* b_scope = (const float*)d_in[4];
    float* out = (float*)d_out;

    fused_kernel<<<dim3(B_ * H_), 256, 0, stream>>>(
        x, w_off, b_off, w_scope, b_scope, out);
}

// Round 4
// 93.944 us; speedup vs baseline: 1.9887x; 1.1481x over previous
//
#include <hip/hip_runtime.h>
#include <math.h>

// Problem constants (B, C, H, W) = (16, 256, 64, 64), GROUPS=4, RATIO=2
#define B_   16
#define C_   256
#define H_   64
#define W_   64
#define G_   4
#define HO_  128
#define WO_  128
#define HW_  (H_ * W_)
#define HOWO_ (HO_ * WO_)

// ---------------------------------------------------------------------------
// Prep: transpose weights into wcomb[t][i2][40]:
//   [0..31]  = w_off[o][t*64+i2]          (o = 0..31)
//   [32..39] = w_scope[t][oi][i2]         (oi = 0..7)
// 40 contiguous floats per (t,i2) -> wide uniform s_loads in the main kernel.
// ---------------------------------------------------------------------------
__global__ __launch_bounds__(256) void prep_kernel(
    const float* __restrict__ w_off,    // (32, 256)
    const float* __restrict__ w_scope,  // (4, 8, 64)
    float* __restrict__ wcomb)          // (4, 64, 40)
{
    const int k = blockIdx.x * 256 + threadIdx.x;
    if (k >= 4 * 64 * 40) return;
    const int q = k % 40;
    const int r = k / 40;
    const int i2 = r & 63;
    const int t  = r >> 6;
    float v;
    if (q < 32) v = w_off[q * 256 + t * 64 + i2];
    else        v = w_scope[t * 512 + (q - 32) * 64 + i2];
    wcomb[k] = v;
}

// ---------------------------------------------------------------------------
// Fused kernel. One block = one input row (b, h). 256 threads = 4 waves.
// Conv phase: wave t (= tid>>6, SGPR) owns channels [64t, 64t+64); lane = w.
//   Weights arrive via uniform s_loads (SGPR broadcast) -> no LDS traffic.
//   aoff partials reduced across waves through a 32 KB LDS buffer
//   (chunk-rotation swizzle keeps both sides conflict-free); asc (scope) for
//   group t is fully wave-owned.
// Sample phase: thread (z=tid>>7, wo=tid&127) covers ho = 2h+z, loops
//   g(4) x cc(64); writes coalesced along wo.
// ---------------------------------------------------------------------------
__global__ __launch_bounds__(256) void fused_kernel(
    const float* __restrict__ x,        // (B, 256, 64, 64)
    const float* __restrict__ wcomb,    // (4, 64, 40)
    const float* __restrict__ b_off,    // (32,)
    const float* __restrict__ b_scope,  // (32,)
    float* __restrict__ out)            // (B, 256, 128, 128)
{
    __shared__ float red[4 * 64 * 32];      // 32 KB partial aoff
    __shared__ float2 coords[4 * 2 * 128];  // 8 KB [g][z][wo]

    const int tid = threadIdx.x;
    const int t = __builtin_amdgcn_readfirstlane(tid >> 6);  // wave id, SGPR
    const int w = tid & 63;                                  // pixel in row
    const int h = blockIdx.x & 63;
    const int b = blockIdx.x >> 6;

    const float* xq = x + (size_t)b * C_ * HW_ + (size_t)t * 64 * HW_ +
                      h * W_ + w;
    const float* wt = wcomb + t * (64 * 40);

    float aoff[32];
    float asc[8];
#pragma unroll
    for (int o = 0; o < 32; ++o) aoff[o] = 0.f;
#pragma unroll
    for (int o = 0; o < 8; ++o) asc[o] = 0.f;

#pragma unroll 2
    for (int i2 = 0; i2 < 64; ++i2) {
        const float xv = xq[(size_t)i2 * HW_];     // coalesced 256 B / wave
        const float* wr = wt + i2 * 40;            // uniform -> s_load
#pragma unroll
        for (int o = 0; o < 32; ++o) aoff[o] += xv * wr[o];
#pragma unroll
        for (int j = 0; j < 8; ++j)  asc[j] += xv * wr[32 + j];
    }

    // ---- cross-wave reduction of aoff through LDS (chunk-rotated) ----
    {
        float4* rw = (float4*)&red[(t * 64 + w) * 32];
#pragma unroll
        for (int j = 0; j < 8; ++j) {
            rw[(j + w) & 7] = make_float4(aoff[4 * j + 0], aoff[4 * j + 1],
                                          aoff[4 * j + 2], aoff[4 * j + 3]);
        }
    }
    __syncthreads();

    // wave t: reduce chunks 2t, 2t+1 (its group's 8 off-channels) for pixel w
    float4 s0 = make_float4(0.f, 0.f, 0.f, 0.f);
    float4 s1 = make_float4(0.f, 0.f, 0.f, 0.f);
#pragma unroll
    for (int tt = 0; tt < 4; ++tt) {
        const float4* rr = (const float4*)&red[(tt * 64 + w) * 32];
        const float4 a = rr[(2 * t + 0 + w) & 7];
        const float4 c = rr[(2 * t + 1 + w) & 7];
        s0.x += a.x; s0.y += a.y; s0.z += a.z; s0.w += a.w;
        s1.x += c.x; s1.y += c.y; s1.z += c.z; s1.w += c.w;
    }

    float f[8];
    {
        float ao[8] = {s0.x, s0.y, s0.z, s0.w, s1.x, s1.y, s1.z, s1.w};
#pragma unroll
        for (int j = 0; j < 8; ++j) {
            const float offv = ao[j] + b_off[8 * t + j];      // uniform bias
            const float scv  = asc[j] + b_scope[8 * t + j];
            const float sg   = 1.f / (1.f + expf(-scv));
            f[j] = sg * 0.5f * offv;
        }
    }

    // coords for group t, pixels (2h+r1, 2w..2w+1); float4 = 2 float2 stores
#pragma unroll
    for (int r1 = 0; r1 < 2; ++r1) {
        float c2[4];
#pragma unroll
        for (int r2 = 0; r2 < 2; ++r2) {
            const int ho = 2 * h + r1;
            const int wo = 2 * w + r2;
            float ix = ((float)wo - 0.5f + f[2 * r1 + r2]) * 0.5f;
            float iy = ((float)ho - 0.5f + f[4 + 2 * r1 + r2]) * 0.5f;
            ix = fminf(fmaxf(ix, 0.f), (float)(W_ - 1));
            iy = fminf(fmaxf(iy, 0.f), (float)(H_ - 1));
            c2[2 * r2 + 0] = ix;
            c2[2 * r2 + 1] = iy;
        }
        float4* cw = (float4*)&coords[t * 256 + r1 * 128 + 2 * w];
        *cw = make_float4(c2[0], c2[1], c2[2], c2[3]);
    }

    __syncthreads();

    // ---------------- phase 2: bilinear sampling ----------------
    const int wo = tid & 127;
    const int z  = tid >> 7;            // 0..1
    const int ho = 2 * h + z;

    const float* xb0 = x + (size_t)b * C_ * HW_;
    float* ob0 = out + (size_t)b * C_ * HOWO_ + ho * WO_ + wo;

#pragma unroll
    for (int g = 0; g < 4; ++g) {
        const float2 c = coords[g * 256 + z * 128 + wo];
        const float ix = c.x, iy = c.y;

        const float x0f = floorf(ix);
        const float y0f = floorf(iy);
        const float wx = ix - x0f;
        const float wy = iy - y0f;
        int x0 = (int)x0f;
        int y0 = (int)y0f;
        x0 = max(0, min(x0, W_ - 1));
        y0 = max(0, min(y0, H_ - 1));
        const int x1 = min(x0 + 1, W_ - 1);
        const int y1 = min(y0 + 1, H_ - 1);

        const float w00 = (1.f - wy) * (1.f - wx);
        const float w01 = (1.f - wy) * wx;
        const float w10 = wy * (1.f - wx);
        const float w11 = wy * wx;

        const int p00 = y0 * W_ + x0;
        const int p01 = y0 * W_ + x1;
        const int p10 = y1 * W_ + x0;
        const int p11 = y1 * W_ + x1;

        const float* xb = xb0 + (size_t)g * HW_;
        float* ob = ob0 + (size_t)g * HOWO_;

#pragma unroll 4
        for (int cc = 0; cc < 64; ++cc) {
            const float* pl = xb + (size_t)cc * 4 * HW_;
            const float v = pl[p00] * w00 + pl[p01] * w01 +
                            pl[p10] * w10 + pl[p11] * w11;
            ob[(size_t)cc * 4 * HOWO_] = v;
        }
    }
}

// ---------------------------------------------------------------------------
extern "C" void kernel_launch(void* const* d_in, const int* in_sizes, int n_in,
                              void* d_out, int out_size, void* d_ws, size_t ws_size,
                              hipStream_t stream) {
    const float* x       = (const float*)d_in[0];
    const float* w_off   = (const float*)d_in[1];
    const float* b_off   = (const float*)d_in[2];
    const float* w_scope = (const float*)d_in[3];
    const float* b_scope = (const float*)d_in[4];
    float* out = (float*)d_out;
    float* wcomb = (float*)d_ws;   // 4*64*40 floats = 40 KB

    prep_kernel<<<dim3(40), 256, 0, stream>>>(w_off, w_scope, wcomb);
    fused_kernel<<<dim3(B_ * H_), 256, 0, stream>>>(
        x, wcomb, b_off, b_scope, out);
}